// Round 7
// baseline (443.615 us; speedup 1.0000x reference)
//
#include <hip/hip_runtime.h>

#define H 256
#define B 4
#define N 64
#define T 256
#define L 5
#define TOPK 8

typedef __attribute__((ext_vector_type(8))) short bf16x8;
typedef __attribute__((ext_vector_type(4))) float f32x4;

__device__ __forceinline__ unsigned short f2bf(float x) {   // RTNE
    unsigned u = __float_as_uint(x);
    return (unsigned short)((u + 0x7fffu + ((u >> 16) & 1u)) >> 16);
}
__device__ __forceinline__ float bf2f(unsigned short h) {
    return __uint_as_float(((unsigned)h) << 16);
}

// ---------------------------------------------------------------------------
// Prep  (EXACT round-4 kernel, known-pass): build per-weight MFMA B-fragment
// arrays in global ws, split into 2 or 3 bf16 terms (h, m[, l]).
//   idx(s, tile, kstep, lane) = ((s*16 + tile)*8 + kstep)*64 + lane
// frag(lane) = W[j = tile*16 + (lane&15)][k = kstep*32 + (lane>>4)*8 + e]
// for C = A@W^T (direct).  For C = A@W (wk), source element is wk[k][j]
// (transposed read via LDS).  Block 80: peer_mask classification.
// ---------------------------------------------------------------------------
__global__ __launch_bounds__(256) void prep_kernel(
    const float* __restrict__ wq, const float* __restrict__ wk,
    const float* __restrict__ wv, const float* __restrict__ w1,
    const float* __restrict__ w2, const unsigned char* __restrict__ mask_raw,
    bf16x8* __restrict__ fragQ, bf16x8* __restrict__ fragK,
    bf16x8* __restrict__ fragV, bf16x8* __restrict__ frag1,
    bf16x8* __restrict__ frag2, int* __restrict__ maskI) {
    int bi = blockIdx.x;
    int tid = threadIdx.x;
    if (bi < 80) {
        int id = bi >> 4, tile = bi & 15;
        const float* src = (id == 0) ? wq : (id == 1) ? wk : (id == 2) ? wv
                          : (id == 3) ? w1 : w2;
        bf16x8* dst = (id == 0) ? fragQ : (id == 1) ? fragK : (id == 2) ? fragV
                     : (id == 3) ? frag1 : frag2;
        int splits = (id < 2) ? 3 : 2;
        int lane = tid & 63;
        __shared__ float Lt[256][20];
        if (id == 1) {   // transposed source: need wk[k][j], stage j-tile in LDS
            int c4 = (tid & 3) * 4;
            for (int rr = 0; rr < 256; rr += 64) {
                int r = rr + (tid >> 2);
                *(float4*)&Lt[r][c4] = *(const float4*)(wk + (size_t)r * H + tile * 16 + c4);
            }
            __syncthreads();
        }
        for (int kk = 0; kk < 2; kk++) {
            int kstep = (tid >> 6) + kk * 4;
            int kbase = kstep * 32 + ((lane >> 4) * 8);
            float x[8];
            if (id == 1) {
                #pragma unroll
                for (int e = 0; e < 8; e++) x[e] = Lt[kbase + e][lane & 15];
            } else {
                int j = tile * 16 + (lane & 15);
                float4 v0 = *(const float4*)(src + (size_t)j * H + kbase);
                float4 v1 = *(const float4*)(src + (size_t)j * H + kbase + 4);
                x[0] = v0.x; x[1] = v0.y; x[2] = v0.z; x[3] = v0.w;
                x[4] = v1.x; x[5] = v1.y; x[6] = v1.z; x[7] = v1.w;
            }
            bf16x8 fh, fm, fl;
            #pragma unroll
            for (int e = 0; e < 8; e++) {
                unsigned short h = f2bf(x[e]);
                float r1 = x[e] - bf2f(h);
                unsigned short m = f2bf(r1);
                fh[e] = (short)h; fm[e] = (short)m;
                if (splits == 3) fl[e] = (short)f2bf(r1 - bf2f(m));
            }
            size_t base = ((size_t)(tile * 8 + kstep)) * 64 + lane;
            dst[base] = fh;
            dst[base + 8192] = fm;
            if (splits == 3) dst[base + 16384] = fl;
        }
        return;
    }
    // --- mask classification (bool bytes / int32 / float32) ---
    __shared__ int nzOff, byteBad, intBad;
    if (tid == 0) { nzOff = 0; byteBad = 0; intBad = 0; }
    __syncthreads();
    unsigned char c = mask_raw[tid];
    if ((tid & 3) && c) atomicOr(&nzOff, 1);
    if (c > 1) atomicOr(&byteBad, 1);
    if (tid < 64) {
        unsigned int iv = ((const unsigned int*)mask_raw)[tid];
        if (iv > 1u) atomicOr(&intBad, 1);
    }
    __syncthreads();
    int v;
    if (nzOff && !byteBad)  v = (mask_raw[tid] != 0);
    else if (!intBad)       v = (((const unsigned int*)mask_raw)[tid] != 0);
    else                    v = (((const float*)mask_raw)[tid] != 0.0f);
    maskI[tid] = v;
}

// ---------------------------------------------------------------------------
// Split-bf16 MFMA GEMM  (EXACT round-4 kernel, known-pass), Q path.
// EPI 0: (x+bias)*0.0625   EPI 1: raw
// ---------------------------------------------------------------------------
template <int SPLITS, int EPI>
__global__ __launch_bounds__(256) void gemm_mfma_kernel(
    const float* __restrict__ A, const bf16x8* __restrict__ Wfrag,
    const float* __restrict__ bias, float* __restrict__ C) {
    int m0 = blockIdx.x * 16;
    int tid = threadIdx.x, lane = tid & 63, w = tid >> 6;
    f32x4 acc[4] = {};
    const float* Abase = A + (size_t)(m0 + (lane & 15)) * H + ((lane >> 4) * 8);
    #pragma unroll 2
    for (int ks = 0; ks < 8; ks++) {
        float4 a0 = *(const float4*)(Abase + ks * 32);
        float4 a1 = *(const float4*)(Abase + ks * 32 + 4);
        float x[8] = {a0.x, a0.y, a0.z, a0.w, a1.x, a1.y, a1.z, a1.w};
        bf16x8 ah, am, al;
        #pragma unroll
        for (int e = 0; e < 8; e++) {
            unsigned short h = f2bf(x[e]);
            float r1 = x[e] - bf2f(h);
            unsigned short m = f2bf(r1);
            ah[e] = (short)h; am[e] = (short)m;
            if (SPLITS == 3) al[e] = (short)f2bf(r1 - bf2f(m));
        }
        bf16x8 bh[4], bm[4], bl[4];
        #pragma unroll
        for (int c = 0; c < 4; c++) {
            size_t base = ((size_t)((w * 4 + c) * 8 + ks)) * 64 + lane;
            bh[c] = Wfrag[base];
            bm[c] = Wfrag[base + 8192];
            if (SPLITS == 3) bl[c] = Wfrag[base + 16384];
        }
        #pragma unroll
        for (int c = 0; c < 4; c++) {
            acc[c] = __builtin_amdgcn_mfma_f32_16x16x32_bf16(ah, bh[c], acc[c], 0, 0, 0);
            acc[c] = __builtin_amdgcn_mfma_f32_16x16x32_bf16(ah, bm[c], acc[c], 0, 0, 0);
            acc[c] = __builtin_amdgcn_mfma_f32_16x16x32_bf16(am, bh[c], acc[c], 0, 0, 0);
            if (SPLITS == 3) {
                acc[c] = __builtin_amdgcn_mfma_f32_16x16x32_bf16(ah, bl[c], acc[c], 0, 0, 0);
                acc[c] = __builtin_amdgcn_mfma_f32_16x16x32_bf16(al, bh[c], acc[c], 0, 0, 0);
                acc[c] = __builtin_amdgcn_mfma_f32_16x16x32_bf16(am, bm[c], acc[c], 0, 0, 0);
            }
        }
    }
    __shared__ float Cl[16][260];
    int rbase = (lane >> 4) * 4;
    #pragma unroll
    for (int c = 0; c < 4; c++) {
        int col = (w * 4 + c) * 16 + (lane & 15);
        #pragma unroll
        for (int r = 0; r < 4; r++) Cl[rbase + r][col] = acc[c][r];
    }
    __syncthreads();
    int r = tid >> 4, cg = tid & 15;
    int m = m0 + r;
    float y[16];
    #pragma unroll
    for (int u = 0; u < 4; u++) {
        float4 v = *(float4*)&Cl[r][cg * 16 + u * 4];
        y[u * 4 + 0] = v.x; y[u * 4 + 1] = v.y; y[u * 4 + 2] = v.z; y[u * 4 + 3] = v.w;
    }
    if (EPI == 0) {
        #pragma unroll
        for (int j = 0; j < 16; j++) y[j] = (y[j] + bias[cg * 16 + j]) * 0.0625f;
    }
    #pragma unroll
    for (int u = 0; u < 4; u++) {
        float4 o = {y[u * 4], y[u * 4 + 1], y[u * 4 + 2], y[u * 4 + 3]};
        *(float4*)&C[(size_t)m * H + cg * 16 + u * 4] = o;
    }
}

// ---------------------------------------------------------------------------
// logits  (EXACT round-4 kernel, known-pass).
// ---------------------------------------------------------------------------
__global__ __launch_bounds__(256) void logits_kernel(
    const float* __restrict__ Qk, const float* __restrict__ peer_h,
    const int* __restrict__ maskI, float* __restrict__ logits) {
    const int lags[L] = {1, 5, 10, 21, 30};
    int bi = blockIdx.x;
    int sec = bi & 7;
    int n = (bi >> 3) & 63;
    int b = bi >> 9;
    int tid = threadIdx.x, wave = tid >> 6, lane = tid & 63;
    int r0 = sec * 32;
    if (sec == 0) {
        const int cum[6] = {0, 1, 6, 16, 37, 67};
        if (tid < 67) {
            int l = 0;
            while (tid >= cum[l + 1]) l++;
            int t = tid - cum[l];
            logits[((size_t)(b * T + t)) * (N * L) + n * L + l] = -__builtin_inff();
        }
    }
    if (!maskI[b * N + n]) {
        if (tid < 32 * L) {
            int tl = tid / 5, l = tid - tl * 5;
            int t = r0 + tl + lags[l];
            if (t < T) logits[((size_t)(b * T + t)) * (N * L) + n * L + l] = -__builtin_inff();
        }
        return;
    }
    __shared__ float part[8][164];
    const float* prow = peer_h + ((size_t)(b * N + n) * T + r0) * H;
    const float* qb = Qk + (size_t)b * T * H;
    #pragma unroll 2
    for (int i = 0; i < 8; i++) {
        int tl = wave * 8 + i;
        float4 p = *(const float4*)(prow + (size_t)tl * H + 4 * lane);
        int tb = r0 + tl;
        float4 q[5];
        #pragma unroll
        for (int l = 0; l < L; l++) {
            int t = tb + lags[l];
            t = (t < T) ? t : (T - 1);           // clamp; garbage never stored
            q[l] = *(const float4*)(qb + (size_t)t * H + 4 * lane);
        }
        #pragma unroll
        for (int l = 0; l < L; l++) {
            float s = fmaf(p.x, q[l].x, fmaf(p.y, q[l].y, fmaf(p.z, q[l].z, p.w * q[l].w)));
            s += __shfl_xor(s, 1, 64);
            s += __shfl_xor(s, 2, 64);
            s += __shfl_xor(s, 4, 64);
            if ((lane & 7) == 0) part[lane >> 3][tl * 5 + l] = s;
        }
    }
    __syncthreads();
    if (tid < 32 * L) {
        int tl = tid / 5, l = tid - tl * 5;
        int t = r0 + tl + lags[l];
        if (t < T) {
            float s = 0.0f;
            #pragma unroll
            for (int g = 0; g < 8; g++) s += part[g][tid];
            logits[((size_t)(b * T + t)) * (N * L) + n * L + l] = s;
        }
    }
}

// ---------------------------------------------------------------------------
// Top-8 + softmax + gather  (EXACT round-4 kernel, known-pass).
// ---------------------------------------------------------------------------
__global__ __launch_bounds__(256) void topk_gather_kernel(
    const float* __restrict__ logits, const float* __restrict__ peer_h,
    float* __restrict__ u, float* __restrict__ sw) {
    const int lags[L] = {1, 5, 10, 21, 30};
    int row = blockIdx.x;            // b*T + t
    int b = row >> 8, t = row & 255;
    int tid = threadIdx.x;
    __shared__ float wS[TOPK];
    __shared__ int idxS[TOPK];
    __shared__ float swS;
    if (tid < 64) {
        int lane = tid;
        const float* lrow = logits + (size_t)row * (N * L);
        float v[5];
        #pragma unroll
        for (int i = 0; i < 5; i++) v[i] = lrow[lane + 64 * i];
        float tv[TOPK]; int tix[TOPK];
        for (int k = 0; k < TOPK; k++) {
            float bv = v[0]; int bidx = lane;
            #pragma unroll
            for (int i = 1; i < 5; i++) {
                if (v[i] > bv) { bv = v[i]; bidx = lane + 64 * i; }
            }
            #pragma unroll
            for (int off = 32; off > 0; off >>= 1) {
                float ov = __shfl_xor(bv, off, 64);
                int   oi = __shfl_xor(bidx, off, 64);
                if (ov > bv || (ov == bv && oi < bidx)) { bv = ov; bidx = oi; }
            }
            tv[k] = bv; tix[k] = bidx;
            if ((bidx & 63) == lane) v[bidx >> 6] = -__builtin_inff();
        }
        if (lane == 0) {
            float m = -__builtin_inff();
            for (int k = 0; k < TOPK; k++)
                if (tv[k] > -__builtin_inff()) m = fmaxf(m, tv[k]);
            float den = 0.0f, w[TOPK];
            for (int k = 0; k < TOPK; k++) {
                w[k] = (tv[k] > -__builtin_inff()) ? expf(tv[k] - m) : 0.0f;
                den += w[k];
            }
            float inv = (den > 0.0f) ? 1.0f / den : 0.0f;
            for (int k = 0; k < TOPK; k++) { wS[k] = w[k] * inv; idxS[k] = tix[k]; }
            swS = (den > 0.0f) ? 1.0f : 0.0f;
        }
    }
    __syncthreads();
    float acc = 0.0f;
    #pragma unroll
    for (int k = 0; k < TOPK; k++) {
        float w = wS[k];
        if (w > 0.0f) {
            int idx = idxS[k];
            int n = idx / L, l = idx % L;
            int tp = t - lags[l];
            acc += w * peer_h[(((size_t)(b * N + n)) * T + tp) * H + tid];
        }
    }
    u[(size_t)row * H + tid] = acc;
    if (tid == 0) sw[row] = swS;
}

// ---------------------------------------------------------------------------
// NEW THIS ROUND (the single change vs round 4): fused tail.
// Per 16-row tile, three 2-split MFMA stages back-to-back:
//   csy = u@wv^T + sw*bv ; h1 = elu(csy@w1^T + b1) ; y = h1@w2^T + b2 + csy
//   out = LN(y)*gamma + beta.
// Intermediates round-trip through LDS (C-layout -> A-frag re-split).
// Barrier audit: sync BEFORE each stage's Cl write protects the previous
// stage's re-split reads; epilogue threads write back only cells they read;
// sync before re-split covers all writers.
// ---------------------------------------------------------------------------
__device__ __forceinline__ void mfma_stage2(
    const bf16x8 ah[8], const bf16x8 am[8], const bf16x8* __restrict__ Wf,
    int lane, int w, f32x4 acc[4]) {
    #pragma unroll 2
    for (int ks = 0; ks < 8; ks++) {
        #pragma unroll
        for (int c = 0; c < 4; c++) {
            size_t base = ((size_t)((w * 4 + c) * 8 + ks)) * 64 + lane;
            bf16x8 bh = Wf[base];
            bf16x8 bm = Wf[base + 8192];
            acc[c] = __builtin_amdgcn_mfma_f32_16x16x32_bf16(ah[ks], bh, acc[c], 0, 0, 0);
            acc[c] = __builtin_amdgcn_mfma_f32_16x16x32_bf16(ah[ks], bm, acc[c], 0, 0, 0);
            acc[c] = __builtin_amdgcn_mfma_f32_16x16x32_bf16(am[ks], bh, acc[c], 0, 0, 0);
        }
    }
}

__global__ __launch_bounds__(256) void tail_fused_kernel(
    const float* __restrict__ u, const bf16x8* __restrict__ fragV,
    const bf16x8* __restrict__ frag1, const bf16x8* __restrict__ frag2,
    const float* __restrict__ bv, const float* __restrict__ b1,
    const float* __restrict__ b2, const float* __restrict__ sw,
    const float* __restrict__ gamma, const float* __restrict__ beta,
    float* __restrict__ out) {
    int m0 = blockIdx.x * 16;
    int tid = threadIdx.x, lane = tid & 63, w = tid >> 6;
    int r = tid >> 4, cg = tid & 15;
    __shared__ float Cl[16][260];
    bf16x8 ah[8], am[8];
    const float* Abase = u + (size_t)(m0 + (lane & 15)) * H + ((lane >> 4) * 8);
    #pragma unroll
    for (int ks = 0; ks < 8; ks++) {
        float4 a0 = *(const float4*)(Abase + ks * 32);
        float4 a1 = *(const float4*)(Abase + ks * 32 + 4);
        float x[8] = {a0.x, a0.y, a0.z, a0.w, a1.x, a1.y, a1.z, a1.w};
        #pragma unroll
        for (int e = 0; e < 8; e++) {
            unsigned short h = f2bf(x[e]);
            ah[ks][e] = (short)h;
            am[ks][e] = (short)f2bf(x[e] - bf2f(h));
        }
    }
    float resid[16];
    #pragma unroll 1
    for (int stage = 0; stage < 3; stage++) {
        f32x4 acc[4] = {};
        mfma_stage2(ah, am, stage == 0 ? fragV : (stage == 1 ? frag1 : frag2),
                    lane, w, acc);
        int rbase = (lane >> 4) * 4;
        __syncthreads();   // protect previous stage's Cl re-split reads
        #pragma unroll
        for (int c = 0; c < 4; c++) {
            int col = (w * 4 + c) * 16 + (lane & 15);
            #pragma unroll
            for (int rr = 0; rr < 4; rr++) Cl[rbase + rr][col] = acc[c][rr];
        }
        __syncthreads();
        float y[16];
        #pragma unroll
        for (int uu = 0; uu < 4; uu++) {
            float4 vv = *(float4*)&Cl[r][cg * 16 + uu * 4];
            y[uu * 4 + 0] = vv.x; y[uu * 4 + 1] = vv.y;
            y[uu * 4 + 2] = vv.z; y[uu * 4 + 3] = vv.w;
        }
        if (stage == 0) {
            float bs = sw[m0 + r];
            #pragma unroll
            for (int j = 0; j < 16; j++) {
                y[j] += bs * bv[cg * 16 + j];
                resid[j] = y[j];
            }
        } else if (stage == 1) {
            #pragma unroll
            for (int j = 0; j < 16; j++) {
                float x = y[j] + b1[cg * 16 + j];
                y[j] = (x > 0.0f) ? x : expm1f(x);
            }
        } else {
            #pragma unroll
            for (int j = 0; j < 16; j++) y[j] += b2[cg * 16 + j] + resid[j];
            float s = 0.0f;
            #pragma unroll
            for (int j = 0; j < 16; j++) s += y[j];
            #pragma unroll
            for (int off = 1; off < 16; off <<= 1) s += __shfl_xor(s, off, 64);
            float mu = s * (1.0f / H);
            float sq = 0.0f;
            #pragma unroll
            for (int j = 0; j < 16; j++) { float d = y[j] - mu; sq += d * d; }
            #pragma unroll
            for (int off = 1; off < 16; off <<= 1) sq += __shfl_xor(sq, off, 64);
            float invs = rsqrtf(sq * (1.0f / H) + 1e-5f);
            #pragma unroll
            for (int j = 0; j < 16; j++)
                y[j] = (y[j] - mu) * invs * gamma[cg * 16 + j] + beta[cg * 16 + j];
            #pragma unroll
            for (int uu = 0; uu < 4; uu++) {
                float4 o = {y[uu * 4], y[uu * 4 + 1], y[uu * 4 + 2], y[uu * 4 + 3]};
                *(float4*)&out[(size_t)(m0 + r) * H + cg * 16 + uu * 4] = o;
            }
            return;
        }
        // write activated y back (same cells this thread read: no hazard)
        #pragma unroll
        for (int uu = 0; uu < 4; uu++) {
            float4 o = {y[uu * 4], y[uu * 4 + 1], y[uu * 4 + 2], y[uu * 4 + 3]};
            *(float4*)&Cl[r][cg * 16 + uu * 4] = o;
        }
        __syncthreads();
        // re-split to next stage's A-frags: A[m=lane&15][k=ks*32+(lane>>4)*8+e]
        #pragma unroll
        for (int ks = 0; ks < 8; ks++) {
            float4 a0 = *(float4*)&Cl[lane & 15][ks * 32 + (lane >> 4) * 8];
            float4 a1 = *(float4*)&Cl[lane & 15][ks * 32 + (lane >> 4) * 8 + 4];
            float x[8] = {a0.x, a0.y, a0.z, a0.w, a1.x, a1.y, a1.z, a1.w};
            #pragma unroll
            for (int e = 0; e < 8; e++) {
                unsigned short h = f2bf(x[e]);
                ah[ks][e] = (short)h;
                am[ks][e] = (short)f2bf(x[e] - bf2f(h));
            }
        }
    }
}

// ---------------------------------------------------------------------------
extern "C" void kernel_launch(void* const* d_in, const int* in_sizes, int n_in,
                              void* d_out, int out_size, void* d_ws, size_t ws_size,
                              hipStream_t stream) {
    const float* target_h = (const float*)d_in[0];
    const float* peer_h   = (const float*)d_in[1];
    const unsigned char* peer_mask = (const unsigned char*)d_in[2];
    const float* wq = (const float*)d_in[3];
    const float* bq = (const float*)d_in[4];
    const float* wk = (const float*)d_in[5];
    // bk (d_in[6]) provably irrelevant: uniform per-(b,t) logit shift.
    const float* wv = (const float*)d_in[7];
    const float* bv = (const float*)d_in[8];
    const float* w1 = (const float*)d_in[9];
    const float* b1 = (const float*)d_in[10];
    const float* w2 = (const float*)d_in[11];
    const float* b2 = (const float*)d_in[12];
    const float* gamma = (const float*)d_in[13];
    const float* beta  = (const float*)d_in[14];
    float* out = (float*)d_out;

    char* ws = (char*)d_ws;
    size_t off = 0;
    auto wsa = [&](size_t bytes) -> void* {
        void* p = ws + off;
        off += (bytes + 255) & ~(size_t)255;
        return p;
    };
    int*    maskI  = (int*)wsa(B * N * sizeof(int));
    bf16x8* fragQ  = (bf16x8*)wsa(3 * 8192 * 16);
    bf16x8* fragK  = (bf16x8*)wsa(3 * 8192 * 16);
    bf16x8* fragV  = (bf16x8*)wsa(2 * 8192 * 16);
    bf16x8* frag1  = (bf16x8*)wsa(2 * 8192 * 16);
    bf16x8* frag2  = (bf16x8*)wsa(2 * 8192 * 16);
    float*  tmp    = (float*)wsa((size_t)B * T * H * 4);
    float*  Qk     = (float*)wsa((size_t)B * T * H * 4);
    float*  logits = (float*)wsa((size_t)B * T * N * L * 4);
    float*  u      = (float*)wsa((size_t)B * T * H * 4);
    float*  sw     = (float*)wsa((size_t)B * T * 4);

    prep_kernel<<<81, 256, 0, stream>>>(wq, wk, wv, w1, w2, peer_mask,
                                        fragQ, fragK, fragV, frag1, frag2, maskI);
    gemm_mfma_kernel<3, 0><<<B * T / 16, 256, 0, stream>>>(target_h, fragQ, bq, tmp);
    gemm_mfma_kernel<3, 1><<<B * T / 16, 256, 0, stream>>>(tmp, fragK, nullptr, Qk);
    logits_kernel<<<B * N * 8, 256, 0, stream>>>(Qk, peer_h, maskI, logits);
    topk_gather_kernel<<<B * T, 256, 0, stream>>>(logits, peer_h, u, sw);
    tail_fused_kernel<<<B * T / 16, 256, 0, stream>>>(u, fragV, frag1, frag2,
                                                      bv, b1, b2, sw, gamma, beta, out);
}

// Round 8
// 197.028 us; speedup vs baseline: 2.2515x; 2.2515x over previous
//
#include <hip/hip_runtime.h>

#define H 256
#define B 4
#define N 64
#define T 256
#define L 5
#define TOPK 8

typedef __attribute__((ext_vector_type(8))) short bf16x8;
typedef __attribute__((ext_vector_type(4))) float f32x4;

__device__ __forceinline__ unsigned short f2bf(float x) {   // RTNE
    unsigned u = __float_as_uint(x);
    return (unsigned short)((u + 0x7fffu + ((u >> 16) & 1u)) >> 16);
}
__device__ __forceinline__ float bf2f(unsigned short h) {
    return __uint_as_float(((unsigned)h) << 16);
}

// ---------------------------------------------------------------------------
// Prep  (EXACT round-4 kernel, known-pass): build per-weight MFMA B-fragment
// arrays in global ws, split into 2 or 3 bf16 terms (h, m[, l]).
//   idx(s, tile, kstep, lane) = ((s*16 + tile)*8 + kstep)*64 + lane
// frag(lane) = W[j = tile*16 + (lane&15)][k = kstep*32 + (lane>>4)*8 + e]
// for C = A@W^T (direct).  For C = A@W (wk), source element is wk[k][j]
// (transposed read via LDS).  Block 80: peer_mask classification.
// ---------------------------------------------------------------------------
__global__ __launch_bounds__(256) void prep_kernel(
    const float* __restrict__ wq, const float* __restrict__ wk,
    const float* __restrict__ wv, const float* __restrict__ w1,
    const float* __restrict__ w2, const unsigned char* __restrict__ mask_raw,
    bf16x8* __restrict__ fragQ, bf16x8* __restrict__ fragK,
    bf16x8* __restrict__ fragV, bf16x8* __restrict__ frag1,
    bf16x8* __restrict__ frag2, int* __restrict__ maskI) {
    int bi = blockIdx.x;
    int tid = threadIdx.x;
    if (bi < 80) {
        int id = bi >> 4, tile = bi & 15;
        const float* src = (id == 0) ? wq : (id == 1) ? wk : (id == 2) ? wv
                          : (id == 3) ? w1 : w2;
        bf16x8* dst = (id == 0) ? fragQ : (id == 1) ? fragK : (id == 2) ? fragV
                     : (id == 3) ? frag1 : frag2;
        int splits = (id < 2) ? 3 : 2;
        int lane = tid & 63;
        __shared__ float Lt[256][20];
        if (id == 1) {   // transposed source: need wk[k][j], stage j-tile in LDS
            int c4 = (tid & 3) * 4;
            for (int rr = 0; rr < 256; rr += 64) {
                int r = rr + (tid >> 2);
                *(float4*)&Lt[r][c4] = *(const float4*)(wk + (size_t)r * H + tile * 16 + c4);
            }
            __syncthreads();
        }
        for (int kk = 0; kk < 2; kk++) {
            int kstep = (tid >> 6) + kk * 4;
            int kbase = kstep * 32 + ((lane >> 4) * 8);
            float x[8];
            if (id == 1) {
                #pragma unroll
                for (int e = 0; e < 8; e++) x[e] = Lt[kbase + e][lane & 15];
            } else {
                int j = tile * 16 + (lane & 15);
                float4 v0 = *(const float4*)(src + (size_t)j * H + kbase);
                float4 v1 = *(const float4*)(src + (size_t)j * H + kbase + 4);
                x[0] = v0.x; x[1] = v0.y; x[2] = v0.z; x[3] = v0.w;
                x[4] = v1.x; x[5] = v1.y; x[6] = v1.z; x[7] = v1.w;
            }
            bf16x8 fh, fm, fl;
            #pragma unroll
            for (int e = 0; e < 8; e++) {
                unsigned short h = f2bf(x[e]);
                float r1 = x[e] - bf2f(h);
                unsigned short m = f2bf(r1);
                fh[e] = (short)h; fm[e] = (short)m;
                if (splits == 3) fl[e] = (short)f2bf(r1 - bf2f(m));
            }
            size_t base = ((size_t)(tile * 8 + kstep)) * 64 + lane;
            dst[base] = fh;
            dst[base + 8192] = fm;
            if (splits == 3) dst[base + 16384] = fl;
        }
        return;
    }
    // --- mask classification (bool bytes / int32 / float32) ---
    __shared__ int nzOff, byteBad, intBad;
    if (tid == 0) { nzOff = 0; byteBad = 0; intBad = 0; }
    __syncthreads();
    unsigned char c = mask_raw[tid];
    if ((tid & 3) && c) atomicOr(&nzOff, 1);
    if (c > 1) atomicOr(&byteBad, 1);
    if (tid < 64) {
        unsigned int iv = ((const unsigned int*)mask_raw)[tid];
        if (iv > 1u) atomicOr(&intBad, 1);
    }
    __syncthreads();
    int v;
    if (nzOff && !byteBad)  v = (mask_raw[tid] != 0);
    else if (!intBad)       v = (((const unsigned int*)mask_raw)[tid] != 0);
    else                    v = (((const float*)mask_raw)[tid] != 0.0f);
    maskI[tid] = v;
}

// ---------------------------------------------------------------------------
// Split-bf16 MFMA GEMM  (EXACT round-4 kernel, known-pass), Q path.
// EPI 0: (x+bias)*0.0625   EPI 1: raw
// ---------------------------------------------------------------------------
template <int SPLITS, int EPI>
__global__ __launch_bounds__(256) void gemm_mfma_kernel(
    const float* __restrict__ A, const bf16x8* __restrict__ Wfrag,
    const float* __restrict__ bias, float* __restrict__ C) {
    int m0 = blockIdx.x * 16;
    int tid = threadIdx.x, lane = tid & 63, w = tid >> 6;
    f32x4 acc[4] = {};
    const float* Abase = A + (size_t)(m0 + (lane & 15)) * H + ((lane >> 4) * 8);
    #pragma unroll 2
    for (int ks = 0; ks < 8; ks++) {
        float4 a0 = *(const float4*)(Abase + ks * 32);
        float4 a1 = *(const float4*)(Abase + ks * 32 + 4);
        float x[8] = {a0.x, a0.y, a0.z, a0.w, a1.x, a1.y, a1.z, a1.w};
        bf16x8 ah, am, al;
        #pragma unroll
        for (int e = 0; e < 8; e++) {
            unsigned short h = f2bf(x[e]);
            float r1 = x[e] - bf2f(h);
            unsigned short m = f2bf(r1);
            ah[e] = (short)h; am[e] = (short)m;
            if (SPLITS == 3) al[e] = (short)f2bf(r1 - bf2f(m));
        }
        bf16x8 bh[4], bm[4], bl[4];
        #pragma unroll
        for (int c = 0; c < 4; c++) {
            size_t base = ((size_t)((w * 4 + c) * 8 + ks)) * 64 + lane;
            bh[c] = Wfrag[base];
            bm[c] = Wfrag[base + 8192];
            if (SPLITS == 3) bl[c] = Wfrag[base + 16384];
        }
        #pragma unroll
        for (int c = 0; c < 4; c++) {
            acc[c] = __builtin_amdgcn_mfma_f32_16x16x32_bf16(ah, bh[c], acc[c], 0, 0, 0);
            acc[c] = __builtin_amdgcn_mfma_f32_16x16x32_bf16(ah, bm[c], acc[c], 0, 0, 0);
            acc[c] = __builtin_amdgcn_mfma_f32_16x16x32_bf16(am, bh[c], acc[c], 0, 0, 0);
            if (SPLITS == 3) {
                acc[c] = __builtin_amdgcn_mfma_f32_16x16x32_bf16(ah, bl[c], acc[c], 0, 0, 0);
                acc[c] = __builtin_amdgcn_mfma_f32_16x16x32_bf16(al, bh[c], acc[c], 0, 0, 0);
                acc[c] = __builtin_amdgcn_mfma_f32_16x16x32_bf16(am, bm[c], acc[c], 0, 0, 0);
            }
        }
    }
    __shared__ float Cl[16][260];
    int rbase = (lane >> 4) * 4;
    #pragma unroll
    for (int c = 0; c < 4; c++) {
        int col = (w * 4 + c) * 16 + (lane & 15);
        #pragma unroll
        for (int r = 0; r < 4; r++) Cl[rbase + r][col] = acc[c][r];
    }
    __syncthreads();
    int r = tid >> 4, cg = tid & 15;
    int m = m0 + r;
    float y[16];
    #pragma unroll
    for (int u = 0; u < 4; u++) {
        float4 v = *(float4*)&Cl[r][cg * 16 + u * 4];
        y[u * 4 + 0] = v.x; y[u * 4 + 1] = v.y; y[u * 4 + 2] = v.z; y[u * 4 + 3] = v.w;
    }
    if (EPI == 0) {
        #pragma unroll
        for (int j = 0; j < 16; j++) y[j] = (y[j] + bias[cg * 16 + j]) * 0.0625f;
    }
    #pragma unroll
    for (int u = 0; u < 4; u++) {
        float4 o = {y[u * 4], y[u * 4 + 1], y[u * 4 + 2], y[u * 4 + 3]};
        *(float4*)&C[(size_t)m * H + cg * 16 + u * 4] = o;
    }
}

// ---------------------------------------------------------------------------
// logits  (EXACT round-4 kernel, known-pass).
// ---------------------------------------------------------------------------
__global__ __launch_bounds__(256) void logits_kernel(
    const float* __restrict__ Qk, const float* __restrict__ peer_h,
    const int* __restrict__ maskI, float* __restrict__ logits) {
    const int lags[L] = {1, 5, 10, 21, 30};
    int bi = blockIdx.x;
    int sec = bi & 7;
    int n = (bi >> 3) & 63;
    int b = bi >> 9;
    int tid = threadIdx.x, wave = tid >> 6, lane = tid & 63;
    int r0 = sec * 32;
    if (sec == 0) {
        const int cum[6] = {0, 1, 6, 16, 37, 67};
        if (tid < 67) {
            int l = 0;
            while (tid >= cum[l + 1]) l++;
            int t = tid - cum[l];
            logits[((size_t)(b * T + t)) * (N * L) + n * L + l] = -__builtin_inff();
        }
    }
    if (!maskI[b * N + n]) {
        if (tid < 32 * L) {
            int tl = tid / 5, l = tid - tl * 5;
            int t = r0 + tl + lags[l];
            if (t < T) logits[((size_t)(b * T + t)) * (N * L) + n * L + l] = -__builtin_inff();
        }
        return;
    }
    __shared__ float part[8][164];
    const float* prow = peer_h + ((size_t)(b * N + n) * T + r0) * H;
    const float* qb = Qk + (size_t)b * T * H;
    #pragma unroll 2
    for (int i = 0; i < 8; i++) {
        int tl = wave * 8 + i;
        float4 p = *(const float4*)(prow + (size_t)tl * H + 4 * lane);
        int tb = r0 + tl;
        float4 q[5];
        #pragma unroll
        for (int l = 0; l < L; l++) {
            int t = tb + lags[l];
            t = (t < T) ? t : (T - 1);           // clamp; garbage never stored
            q[l] = *(const float4*)(qb + (size_t)t * H + 4 * lane);
        }
        #pragma unroll
        for (int l = 0; l < L; l++) {
            float s = fmaf(p.x, q[l].x, fmaf(p.y, q[l].y, fmaf(p.z, q[l].z, p.w * q[l].w)));
            s += __shfl_xor(s, 1, 64);
            s += __shfl_xor(s, 2, 64);
            s += __shfl_xor(s, 4, 64);
            if ((lane & 7) == 0) part[lane >> 3][tl * 5 + l] = s;
        }
    }
    __syncthreads();
    if (tid < 32 * L) {
        int tl = tid / 5, l = tid - tl * 5;
        int t = r0 + tl + lags[l];
        if (t < T) {
            float s = 0.0f;
            #pragma unroll
            for (int g = 0; g < 8; g++) s += part[g][tid];
            logits[((size_t)(b * T + t)) * (N * L) + n * L + l] = s;
        }
    }
}

// ---------------------------------------------------------------------------
// Top-8 + softmax + gather  (EXACT round-4 kernel, known-pass).
// ---------------------------------------------------------------------------
__global__ __launch_bounds__(256) void topk_gather_kernel(
    const float* __restrict__ logits, const float* __restrict__ peer_h,
    float* __restrict__ u, float* __restrict__ sw) {
    const int lags[L] = {1, 5, 10, 21, 30};
    int row = blockIdx.x;            // b*T + t
    int b = row >> 8, t = row & 255;
    int tid = threadIdx.x;
    __shared__ float wS[TOPK];
    __shared__ int idxS[TOPK];
    __shared__ float swS;
    if (tid < 64) {
        int lane = tid;
        const float* lrow = logits + (size_t)row * (N * L);
        float v[5];
        #pragma unroll
        for (int i = 0; i < 5; i++) v[i] = lrow[lane + 64 * i];
        float tv[TOPK]; int tix[TOPK];
        for (int k = 0; k < TOPK; k++) {
            float bv = v[0]; int bidx = lane;
            #pragma unroll
            for (int i = 1; i < 5; i++) {
                if (v[i] > bv) { bv = v[i]; bidx = lane + 64 * i; }
            }
            #pragma unroll
            for (int off = 32; off > 0; off >>= 1) {
                float ov = __shfl_xor(bv, off, 64);
                int   oi = __shfl_xor(bidx, off, 64);
                if (ov > bv || (ov == bv && oi < bidx)) { bv = ov; bidx = oi; }
            }
            tv[k] = bv; tix[k] = bidx;
            if ((bidx & 63) == lane) v[bidx >> 6] = -__builtin_inff();
        }
        if (lane == 0) {
            float m = -__builtin_inff();
            for (int k = 0; k < TOPK; k++)
                if (tv[k] > -__builtin_inff()) m = fmaxf(m, tv[k]);
            float den = 0.0f, w[TOPK];
            for (int k = 0; k < TOPK; k++) {
                w[k] = (tv[k] > -__builtin_inff()) ? expf(tv[k] - m) : 0.0f;
                den += w[k];
            }
            float inv = (den > 0.0f) ? 1.0f / den : 0.0f;
            for (int k = 0; k < TOPK; k++) { wS[k] = w[k] * inv; idxS[k] = tix[k]; }
            swS = (den > 0.0f) ? 1.0f : 0.0f;
        }
    }
    __syncthreads();
    float acc = 0.0f;
    #pragma unroll
    for (int k = 0; k < TOPK; k++) {
        float w = wS[k];
        if (w > 0.0f) {
            int idx = idxS[k];
            int n = idx / L, l = idx % L;
            int tp = t - lags[l];
            acc += w * peer_h[(((size_t)(b * N + n)) * T + tp) * H + tid];
        }
    }
    u[(size_t)row * H + tid] = acc;
    if (tid == 0) sw[row] = swS;
}

// ---------------------------------------------------------------------------
// Fused tail (round-7 structure; FIX: ks-loop fully unrolled so ah[]/am[]
// have only compile-time indices -> stay in VGPRs, no scratch spill).
//   csy = u@wv^T + sw*bv ; h1 = elu(csy@w1^T + b1) ; y = h1@w2^T + b2 + csy
//   out = LN(y)*gamma + beta.
// ---------------------------------------------------------------------------
__device__ __forceinline__ void mfma_stage2(
    const bf16x8 ah[8], const bf16x8 am[8], const bf16x8* __restrict__ Wf,
    int lane, int w, f32x4 acc[4]) {
    #pragma unroll
    for (int ks = 0; ks < 8; ks++) {        // FULL unroll: static ah/am indices
        #pragma unroll
        for (int c = 0; c < 4; c++) {
            size_t base = ((size_t)((w * 4 + c) * 8 + ks)) * 64 + lane;
            bf16x8 bh = Wf[base];
            bf16x8 bm = Wf[base + 8192];
            acc[c] = __builtin_amdgcn_mfma_f32_16x16x32_bf16(ah[ks], bh, acc[c], 0, 0, 0);
            acc[c] = __builtin_amdgcn_mfma_f32_16x16x32_bf16(ah[ks], bm, acc[c], 0, 0, 0);
            acc[c] = __builtin_amdgcn_mfma_f32_16x16x32_bf16(am[ks], bh, acc[c], 0, 0, 0);
        }
    }
}

__global__ __launch_bounds__(256) void tail_fused_kernel(
    const float* __restrict__ u, const bf16x8* __restrict__ fragV,
    const bf16x8* __restrict__ frag1, const bf16x8* __restrict__ frag2,
    const float* __restrict__ bv, const float* __restrict__ b1,
    const float* __restrict__ b2, const float* __restrict__ sw,
    const float* __restrict__ gamma, const float* __restrict__ beta,
    float* __restrict__ out) {
    int m0 = blockIdx.x * 16;
    int tid = threadIdx.x, lane = tid & 63, w = tid >> 6;
    int r = tid >> 4, cg = tid & 15;
    __shared__ float Cl[16][260];
    bf16x8 ah[8], am[8];
    const float* Abase = u + (size_t)(m0 + (lane & 15)) * H + ((lane >> 4) * 8);
    #pragma unroll
    for (int ks = 0; ks < 8; ks++) {
        float4 a0 = *(const float4*)(Abase + ks * 32);
        float4 a1 = *(const float4*)(Abase + ks * 32 + 4);
        float x[8] = {a0.x, a0.y, a0.z, a0.w, a1.x, a1.y, a1.z, a1.w};
        #pragma unroll
        for (int e = 0; e < 8; e++) {
            unsigned short h = f2bf(x[e]);
            ah[ks][e] = (short)h;
            am[ks][e] = (short)f2bf(x[e] - bf2f(h));
        }
    }
    float resid[16];
    #pragma unroll 1
    for (int stage = 0; stage < 3; stage++) {
        f32x4 acc[4] = {};
        mfma_stage2(ah, am, stage == 0 ? fragV : (stage == 1 ? frag1 : frag2),
                    lane, w, acc);
        int rbase = (lane >> 4) * 4;
        __syncthreads();   // protect previous stage's Cl re-split reads
        #pragma unroll
        for (int c = 0; c < 4; c++) {
            int col = (w * 4 + c) * 16 + (lane & 15);
            #pragma unroll
            for (int rr = 0; rr < 4; rr++) Cl[rbase + rr][col] = acc[c][rr];
        }
        __syncthreads();
        float y[16];
        #pragma unroll
        for (int uu = 0; uu < 4; uu++) {
            float4 vv = *(float4*)&Cl[r][cg * 16 + uu * 4];
            y[uu * 4 + 0] = vv.x; y[uu * 4 + 1] = vv.y;
            y[uu * 4 + 2] = vv.z; y[uu * 4 + 3] = vv.w;
        }
        if (stage == 0) {
            float bs = sw[m0 + r];
            #pragma unroll
            for (int j = 0; j < 16; j++) {
                y[j] += bs * bv[cg * 16 + j];
                resid[j] = y[j];
            }
        } else if (stage == 1) {
            #pragma unroll
            for (int j = 0; j < 16; j++) {
                float x = y[j] + b1[cg * 16 + j];
                y[j] = (x > 0.0f) ? x : expm1f(x);
            }
        } else {
            #pragma unroll
            for (int j = 0; j < 16; j++) y[j] += b2[cg * 16 + j] + resid[j];
            float s = 0.0f;
            #pragma unroll
            for (int j = 0; j < 16; j++) s += y[j];
            #pragma unroll
            for (int off = 1; off < 16; off <<= 1) s += __shfl_xor(s, off, 64);
            float mu = s * (1.0f / H);
            float sq = 0.0f;
            #pragma unroll
            for (int j = 0; j < 16; j++) { float d = y[j] - mu; sq += d * d; }
            #pragma unroll
            for (int off = 1; off < 16; off <<= 1) sq += __shfl_xor(sq, off, 64);
            float invs = rsqrtf(sq * (1.0f / H) + 1e-5f);
            #pragma unroll
            for (int j = 0; j < 16; j++)
                y[j] = (y[j] - mu) * invs * gamma[cg * 16 + j] + beta[cg * 16 + j];
            #pragma unroll
            for (int uu = 0; uu < 4; uu++) {
                float4 o = {y[uu * 4], y[uu * 4 + 1], y[uu * 4 + 2], y[uu * 4 + 3]};
                *(float4*)&out[(size_t)(m0 + r) * H + cg * 16 + uu * 4] = o;
            }
            return;
        }
        // write activated y back (same cells this thread read: no hazard)
        #pragma unroll
        for (int uu = 0; uu < 4; uu++) {
            float4 o = {y[uu * 4], y[uu * 4 + 1], y[uu * 4 + 2], y[uu * 4 + 3]};
            *(float4*)&Cl[r][cg * 16 + uu * 4] = o;
        }
        __syncthreads();
        // re-split to next stage's A-frags: A[m=lane&15][k=ks*32+(lane>>4)*8+e]
        #pragma unroll
        for (int ks = 0; ks < 8; ks++) {
            float4 a0 = *(float4*)&Cl[lane & 15][ks * 32 + (lane >> 4) * 8];
            float4 a1 = *(float4*)&Cl[lane & 15][ks * 32 + (lane >> 4) * 8 + 4];
            float x[8] = {a0.x, a0.y, a0.z, a0.w, a1.x, a1.y, a1.z, a1.w};
            #pragma unroll
            for (int e = 0; e < 8; e++) {
                unsigned short h = f2bf(x[e]);
                ah[ks][e] = (short)h;
                am[ks][e] = (short)f2bf(x[e] - bf2f(h));
            }
        }
    }
}

// ---------------------------------------------------------------------------
extern "C" void kernel_launch(void* const* d_in, const int* in_sizes, int n_in,
                              void* d_out, int out_size, void* d_ws, size_t ws_size,
                              hipStream_t stream) {
    const float* target_h = (const float*)d_in[0];
    const float* peer_h   = (const float*)d_in[1];
    const unsigned char* peer_mask = (const unsigned char*)d_in[2];
    const float* wq = (const float*)d_in[3];
    const float* bq = (const float*)d_in[4];
    const float* wk = (const float*)d_in[5];
    // bk (d_in[6]) provably irrelevant: uniform per-(b,t) logit shift.
    const float* wv = (const float*)d_in[7];
    const float* bv = (const float*)d_in[8];
    const float* w1 = (const float*)d_in[9];
    const float* b1 = (const float*)d_in[10];
    const float* w2 = (const float*)d_in[11];
    const float* b2 = (const float*)d_in[12];
    const float* gamma = (const float*)d_in[13];
    const float* beta  = (const float*)d_in[14];
    float* out = (float*)d_out;

    char* ws = (char*)d_ws;
    size_t off = 0;
    auto wsa = [&](size_t bytes) -> void* {
        void* p = ws + off;
        off += (bytes + 255) & ~(size_t)255;
        return p;
    };
    int*    maskI  = (int*)wsa(B * N * sizeof(int));
    bf16x8* fragQ  = (bf16x8*)wsa(3 * 8192 * 16);
    bf16x8* fragK  = (bf16x8*)wsa(3 * 8192 * 16);
    bf16x8* fragV  = (bf16x8*)wsa(2 * 8192 * 16);
    bf16x8* frag1  = (bf16x8*)wsa(2 * 8192 * 16);
    bf16x8* frag2  = (bf16x8*)wsa(2 * 8192 * 16);
    float*  tmp    = (float*)wsa((size_t)B * T * H * 4);
    float*  Qk     = (float*)wsa((size_t)B * T * H * 4);
    float*  logits = (float*)wsa((size_t)B * T * N * L * 4);
    float*  u      = (float*)wsa((size_t)B * T * H * 4);
    float*  sw     = (float*)wsa((size_t)B * T * 4);

    prep_kernel<<<81, 256, 0, stream>>>(wq, wk, wv, w1, w2, peer_mask,
                                        fragQ, fragK, fragV, frag1, frag2, maskI);
    gemm_mfma_kernel<3, 0><<<B * T / 16, 256, 0, stream>>>(target_h, fragQ, bq, tmp);
    gemm_mfma_kernel<3, 1><<<B * T / 16, 256, 0, stream>>>(tmp, fragK, nullptr, Qk);
    logits_kernel<<<B * N * 8, 256, 0, stream>>>(Qk, peer_h, maskI, logits);
    topk_gather_kernel<<<B * T, 256, 0, stream>>>(logits, peer_h, u, sw);
    tail_fused_kernel<<<B * T / 16, 256, 0, stream>>>(u, fragV, frag1, frag2,
                                                      bv, b1, b2, sw, gamma, beta, out);
}